// Round 1
// baseline (259.248 us; speedup 1.0000x reference)
//
#include <hip/hip_runtime.h>
#include <math.h>

#define CC 128
#define HH 32
#define WW 32
#define HW (HH*WW)
#define PP (CC*HW)          // 131072 per level
#define NL 3
#define NP (NL*PP)          // 393216 total keypoints

// d_out layout (floats), concat in return order
#define KP_OFF   0                    // [NP,2]
#define DESC_OFF (NP*2)               // [NP,128]
#define SC_OFF   (DESC_OFF + (size_t)NP*CC) // [NP]
#define MK_OFF   (SC_OFF + NP)        // [NP]

// ws layout (floats)
#define WS_KI   ((size_t)0)
#define WS_KJ   ((size_t)NP)
#define WS_MV   ((size_t)2*NP)
#define WS_FT   ((size_t)3*NP)        // transposed features, [level][H*W][C], NP floats total
#define WS_SUM  ((size_t)4*NP)        // 3 floats: per-level score sum-of-squares

__global__ __launch_bounds__(64) void zero_sums(float* ws) {
    if (threadIdx.x < NL) ws[WS_SUM + threadIdx.x] = 0.0f;
}

__global__ __launch_bounds__(256) void prep_kernel(
    const float* __restrict__ f0, const float* __restrict__ f1, const float* __restrict__ f2,
    const float* __restrict__ s0, const float* __restrict__ s1, const float* __restrict__ s2,
    float* __restrict__ out, float* __restrict__ ws)
{
    const int g = blockIdx.x * 256 + threadIdx.x;     // [0, NP)
    const int level = g / PP;                          // uniform per block (512 blocks/level)
    const int p = g - level * PP;
    const float* __restrict__ f  = (level == 0) ? f0 : (level == 1) ? f1 : f2;
    const float* __restrict__ sc = (level == 0) ? s0 : (level == 1) ? s1 : s2;

    const int c   = p >> 10;          // p / 1024
    const int rem = p & 1023;         // i*32 + j
    const int i   = rem >> 5;
    const int j   = rem & 31;

    const float fc = f[p];
    const float* __restrict__ fb = f + (c << 10);

    // zero-padded 3x3 stencil
    #define LD(ii, jj) (((ii) >= 0 && (ii) < HH && (jj) >= 0 && (jj) < WW) ? fb[(ii)*WW + (jj)] : 0.0f)
    const float fN  = LD(i-1, j  );
    const float fS  = LD(i+1, j  );
    const float fWv = LD(i  , j-1);
    const float fE  = LD(i  , j+1);
    const float fNW = LD(i-1, j-1);
    const float fNE = LD(i-1, j+1);
    const float fSW = LD(i+1, j-1);
    const float fSE = LD(i+1, j+1);
    #undef LD

    // Replicate numpy fp32 IEEE evaluation exactly (no FMA contraction).
    const float di  = __fmul_rn(0.5f, __fsub_rn(fS, fN));
    const float dj  = __fmul_rn(0.5f, __fsub_rn(fE, fWv));
    const float dii = __fadd_rn(__fsub_rn(fS, __fmul_rn(2.0f, fc)), fN);
    const float djj = __fadd_rn(__fsub_rn(fE, __fmul_rn(2.0f, fc)), fWv);
    const float dij = __fmul_rn(0.25f, __fadd_rn(__fsub_rn(__fsub_rn(fNW, fNE), fSW), fSE));

    const float det = __fsub_rn(__fmul_rn(dii, djj), __fmul_rn(dij, dij));
    const bool det_ok = fabsf(det) > 1e-10f;
    const float det_s = det_ok ? det : 1.0f;
    const float t1 = __fsub_rn(__fmul_rn(djj, di), __fmul_rn(dij, dj));
    const float disp_i = __fdiv_rn(-t1, det_s);
    const float t2 = __fadd_rn(-__fmul_rn(dij, di), __fmul_rn(dii, dj));
    const float disp_j = __fdiv_rn(-t2, det_s);
    const bool disp_ok = det_ok && (fabsf(disp_i) < 0.5f) && (fabsf(disp_j) < 0.5f);

    const float sraw = sc[p];
    const float sth = (sraw < 0.5f) ? 0.0f : sraw;
    const bool det_mask = (sth != 0.0f);

    const float ki = __fadd_rn(disp_ok ? disp_i : 0.0f, (float)i);
    const float kj = __fadd_rn(disp_ok ? disp_j : 0.0f, (float)j);
    const float i0 = floorf(ki), i1 = ceilf(ki);
    const float j0 = floorf(kj), j1 = ceilf(kj);
    const bool in_b = (i0 >= 0.0f) && (i1 <= (float)(HH-1)) && (j0 >= 0.0f) && (j1 <= (float)(WW-1));
    const bool mask = det_mask && disp_ok && in_b;
    const float mf = mask ? 1.0f : 0.0f;

    // keypoints: kp = k*16 + 7.5, masked
    out[KP_OFF + 2*(size_t)g    ] = mask ? __fadd_rn(__fmul_rn(ki, 16.0f), 7.5f) : 0.0f;
    out[KP_OFF + 2*(size_t)g + 1] = mask ? __fadd_rn(__fmul_rn(kj, 16.0f), 7.5f) : 0.0f;
    out[MK_OFF + g] = mf;

    const float sm = mask ? sth : 0.0f;
    out[SC_OFF + g] = sm;          // unnormalized; scale_kernel fixes it up

    ws[WS_KI + g] = ki;
    ws[WS_KJ + g] = kj;
    ws[WS_MV + g] = mf;
    ws[WS_FT + (size_t)level*PP + (size_t)rem*CC + c] = fc;   // [H,W,C] transpose

    // per-level sum of squares of masked scores
    float v = __fmul_rn(sm, sm);
    #pragma unroll
    for (int off = 32; off > 0; off >>= 1) v += __shfl_xor(v, off);
    __shared__ float red[4];
    const int wid = threadIdx.x >> 6;
    const int lane = threadIdx.x & 63;
    if (lane == 0) red[wid] = v;
    __syncthreads();
    if (threadIdx.x == 0) {
        float t = red[0] + red[1] + red[2] + red[3];
        atomicAdd(&ws[WS_SUM + level], t);
    }
}

__global__ __launch_bounds__(256) void scale_kernel(float* __restrict__ out, const float* __restrict__ ws)
{
    const int g = blockIdx.x * 256 + threadIdx.x;
    const int level = g / PP;
    const float denom = fmaxf(__fsqrt_rn(ws[WS_SUM + level]), 1e-12f);
    out[SC_OFF + g] = __fdiv_rn(out[SC_OFF + g], denom);
}

__global__ __launch_bounds__(256) void desc_kernel(const float* __restrict__ ws, float* __restrict__ out)
{
    const int wid  = threadIdx.x >> 6;
    const int lane = threadIdx.x & 63;
    const int g = blockIdx.x * 4 + wid;               // one wave per keypoint row

    float* __restrict__ dst = out + DESC_OFF + (size_t)g * CC + 2*lane;
    const float mf = ws[WS_MV + g];
    if (mf == 0.0f) {
        *(float2*)dst = make_float2(0.0f, 0.0f);
        return;
    }

    const int level = g / PP;
    const float ki = ws[WS_KI + g];
    const float kj = ws[WS_KJ + g];
    const float i0 = floorf(ki), i1 = ceilf(ki);
    const float j0 = floorf(kj), j1 = ceilf(kj);
    // mask==1 implies in-bounds; clamp is a no-op kept for safety
    const int i0c = min(max((int)i0, 0), HH-1);
    const int i1c = min(max((int)i1, 0), HH-1);
    const int j0c = min(max((int)j0, 0), WW-1);
    const int j1c = min(max((int)j1, 0), WW-1);
    const float di_ = ki - i0;
    const float dj_ = kj - j0;
    const float wtl = (1.0f - di_) * (1.0f - dj_);
    const float wtr = (1.0f - di_) * dj_;
    const float wbl = di_ * (1.0f - dj_);
    const float wbr = di_ * dj_;

    const float* __restrict__ ft = ws + WS_FT + (size_t)level * PP;
    const float2 tl = *((const float2*)(ft + ((size_t)(i0c*WW + j0c)) * CC) + lane);
    const float2 tr = *((const float2*)(ft + ((size_t)(i0c*WW + j1c)) * CC) + lane);
    const float2 bl = *((const float2*)(ft + ((size_t)(i1c*WW + j0c)) * CC) + lane);
    const float2 br = *((const float2*)(ft + ((size_t)(i1c*WW + j1c)) * CC) + lane);

    const float d0 = wtl*tl.x + wtr*tr.x + wbl*bl.x + wbr*br.x;
    const float d1 = wtl*tl.y + wtr*tr.y + wbl*bl.y + wbr*br.y;

    float ss = d0*d0 + d1*d1;
    #pragma unroll
    for (int off = 32; off > 0; off >>= 1) ss += __shfl_xor(ss, off);
    const float denom = fmaxf(sqrtf(ss), 1e-12f);

    *(float2*)dst = make_float2(__fdiv_rn(d0, denom), __fdiv_rn(d1, denom));
}

extern "C" void kernel_launch(void* const* d_in, const int* in_sizes, int n_in,
                              void* d_out, int out_size, void* d_ws, size_t ws_size,
                              hipStream_t stream) {
    (void)in_sizes; (void)n_in; (void)out_size; (void)ws_size;
    const float* f0 = (const float*)d_in[0];
    const float* f1 = (const float*)d_in[1];
    const float* f2 = (const float*)d_in[2];
    const float* s0 = (const float*)d_in[3];
    const float* s1 = (const float*)d_in[4];
    const float* s2 = (const float*)d_in[5];
    float* out = (float*)d_out;
    float* ws  = (float*)d_ws;

    zero_sums<<<1, 64, 0, stream>>>(ws);
    prep_kernel<<<NP/256, 256, 0, stream>>>(f0, f1, f2, s0, s1, s2, out, ws);
    scale_kernel<<<NP/256, 256, 0, stream>>>(out, ws);
    desc_kernel<<<NP/4, 256, 0, stream>>>(ws, out);
}

// Round 2
// 242.705 us; speedup vs baseline: 1.0682x; 1.0682x over previous
//
#include <hip/hip_runtime.h>
#include <math.h>

#define CC 128
#define HH 32
#define WW 32
#define HW (HH*WW)
#define PP (CC*HW)          // 131072 per level (2^17)
#define NL 3
#define NP (NL*PP)          // 393216 total keypoints

// d_out layout (floats), concat in return order
#define KP_OFF   0                    // [NP,2]
#define DESC_OFF (NP*2)               // [NP,128]
#define SC_OFF   (DESC_OFF + (size_t)NP*CC) // [NP]
#define MK_OFF   (SC_OFF + NP)        // [NP]

// ws layout (floats)
#define WS_KI   ((size_t)0)
#define WS_KJ   ((size_t)NP)
#define WS_MV   ((size_t)2*NP)
#define WS_FT   ((size_t)3*NP)        // transposed features, [level][H*W][C]
#define WS_SUM  ((size_t)4*NP)        // 3 floats: per-level score sum-of-squares

__global__ __launch_bounds__(64) void zero_sums(float* ws) {
    if (threadIdx.x < NL) ws[WS_SUM + threadIdx.x] = 0.0f;
}

__global__ __launch_bounds__(256) void prep_kernel(
    const float* __restrict__ f0, const float* __restrict__ f1, const float* __restrict__ f2,
    const float* __restrict__ s0, const float* __restrict__ s1, const float* __restrict__ s2,
    float* __restrict__ out, float* __restrict__ ws)
{
    const int g = blockIdx.x * 256 + threadIdx.x;     // [0, NP)
    const int level = g >> 17;                         // uniform per block
    const int p = g & (PP - 1);
    const float* __restrict__ f  = (level == 0) ? f0 : (level == 1) ? f1 : f2;
    const float* __restrict__ sc = (level == 0) ? s0 : (level == 1) ? s1 : s2;

    const int c   = p >> 10;          // p / 1024
    const int rem = p & 1023;         // i*32 + j
    const int i   = rem >> 5;
    const int j   = rem & 31;

    const float fc = f[p];
    const float* __restrict__ fb = f + (c << 10);

    // zero-padded 3x3 stencil
    #define LD(ii, jj) (((ii) >= 0 && (ii) < HH && (jj) >= 0 && (jj) < WW) ? fb[(ii)*WW + (jj)] : 0.0f)
    const float fN  = LD(i-1, j  );
    const float fS  = LD(i+1, j  );
    const float fWv = LD(i  , j-1);
    const float fE  = LD(i  , j+1);
    const float fNW = LD(i-1, j-1);
    const float fNE = LD(i-1, j+1);
    const float fSW = LD(i+1, j-1);
    const float fSE = LD(i+1, j+1);
    #undef LD

    // Replicate numpy fp32 IEEE evaluation exactly (no FMA contraction).
    const float di  = __fmul_rn(0.5f, __fsub_rn(fS, fN));
    const float dj  = __fmul_rn(0.5f, __fsub_rn(fE, fWv));
    const float dii = __fadd_rn(__fsub_rn(fS, __fmul_rn(2.0f, fc)), fN);
    const float djj = __fadd_rn(__fsub_rn(fE, __fmul_rn(2.0f, fc)), fWv);
    const float dij = __fmul_rn(0.25f, __fadd_rn(__fsub_rn(__fsub_rn(fNW, fNE), fSW), fSE));

    const float det = __fsub_rn(__fmul_rn(dii, djj), __fmul_rn(dij, dij));
    const bool det_ok = fabsf(det) > 1e-10f;
    const float det_s = det_ok ? det : 1.0f;
    const float t1 = __fsub_rn(__fmul_rn(djj, di), __fmul_rn(dij, dj));
    const float disp_i = __fdiv_rn(-t1, det_s);
    const float t2 = __fadd_rn(-__fmul_rn(dij, di), __fmul_rn(dii, dj));
    const float disp_j = __fdiv_rn(-t2, det_s);
    const bool disp_ok = det_ok && (fabsf(disp_i) < 0.5f) && (fabsf(disp_j) < 0.5f);

    const float sraw = sc[p];
    const float sth = (sraw < 0.5f) ? 0.0f : sraw;
    const bool det_mask = (sth != 0.0f);

    const float ki = __fadd_rn(disp_ok ? disp_i : 0.0f, (float)i);
    const float kj = __fadd_rn(disp_ok ? disp_j : 0.0f, (float)j);
    const float i0 = floorf(ki), i1 = ceilf(ki);
    const float j0 = floorf(kj), j1 = ceilf(kj);
    const bool in_b = (i0 >= 0.0f) && (i1 <= (float)(HH-1)) && (j0 >= 0.0f) && (j1 <= (float)(WW-1));
    const bool mask = det_mask && disp_ok && in_b;
    const float mf = mask ? 1.0f : 0.0f;

    // keypoints: kp = k*16 + 7.5, masked — packed 8B store
    float2 kpv;
    kpv.x = mask ? __fadd_rn(__fmul_rn(ki, 16.0f), 7.5f) : 0.0f;
    kpv.y = mask ? __fadd_rn(__fmul_rn(kj, 16.0f), 7.5f) : 0.0f;
    *(float2*)(out + KP_OFF + 2*(size_t)g) = kpv;
    out[MK_OFF + g] = mf;

    const float sm = mask ? sth : 0.0f;
    out[SC_OFF + g] = sm;          // unnormalized; scale_kernel fixes it up

    ws[WS_KI + g] = ki;
    ws[WS_KJ + g] = kj;
    ws[WS_MV + g] = mf;
    ws[WS_FT + (size_t)level*PP + (size_t)rem*CC + c] = fc;   // [H,W,C] transpose

    // per-level sum of squares of masked scores
    float v = __fmul_rn(sm, sm);
    #pragma unroll
    for (int off = 32; off > 0; off >>= 1) v += __shfl_xor(v, off);
    __shared__ float red[4];
    const int wid = threadIdx.x >> 6;
    const int lane = threadIdx.x & 63;
    if (lane == 0) red[wid] = v;
    __syncthreads();
    if (threadIdx.x == 0) {
        float t = red[0] + red[1] + red[2] + red[3];
        atomicAdd(&ws[WS_SUM + level], t);
    }
}

__global__ __launch_bounds__(256) void scale_kernel(float* __restrict__ out, const float* __restrict__ ws)
{
    const int g = blockIdx.x * 256 + threadIdx.x;
    const int level = g >> 17;
    const float denom = fmaxf(__fsqrt_rn(ws[WS_SUM + level]), 1e-12f);
    out[SC_OFF + g] = __fdiv_rn(out[SC_OFF + g], denom);
}

// 32 lanes per row, float4 per lane; 8 rows per block-iteration; grid-stride.
#define DESC_BLOCKS 3072
__global__ __launch_bounds__(256) void desc_kernel(const float* __restrict__ ws, float* __restrict__ out)
{
    const int sub    = threadIdx.x >> 5;   // row slot within block [0,8)
    const int lane32 = threadIdx.x & 31;

    for (int base = blockIdx.x * 8; base < NP; base += DESC_BLOCKS * 8) {
        const int g = base + sub;
        float4 d = make_float4(0.0f, 0.0f, 0.0f, 0.0f);

        const float mf = ws[WS_MV + g];
        if (mf != 0.0f) {
            const int level = g >> 17;
            const float ki = ws[WS_KI + g];
            const float kj = ws[WS_KJ + g];
            const float i0 = floorf(ki), i1 = ceilf(ki);
            const float j0 = floorf(kj), j1 = ceilf(kj);
            const int i0c = (int)i0, i1c = (int)i1;
            const int j0c = (int)j0, j1c = (int)j1;   // mask==1 implies in-bounds
            const float di_ = ki - i0;
            const float dj_ = kj - j0;
            const float wtl = (1.0f - di_) * (1.0f - dj_);
            const float wtr = (1.0f - di_) * dj_;
            const float wbl = di_ * (1.0f - dj_);
            const float wbr = di_ * dj_;

            const float* __restrict__ ft = ws + WS_FT + (size_t)level * PP;
            const float4 tl = *((const float4*)(ft + ((size_t)(i0c*WW + j0c)) * CC) + lane32);
            const float4 tr = *((const float4*)(ft + ((size_t)(i0c*WW + j1c)) * CC) + lane32);
            const float4 bl = *((const float4*)(ft + ((size_t)(i1c*WW + j0c)) * CC) + lane32);
            const float4 br = *((const float4*)(ft + ((size_t)(i1c*WW + j1c)) * CC) + lane32);

            d.x = wtl*tl.x + wtr*tr.x + wbl*bl.x + wbr*br.x;
            d.y = wtl*tl.y + wtr*tr.y + wbl*bl.y + wbr*br.y;
            d.z = wtl*tl.z + wtr*tr.z + wbl*bl.z + wbr*br.z;
            d.w = wtl*tl.w + wtr*tr.w + wbl*bl.w + wbr*br.w;

            float ss = d.x*d.x + d.y*d.y + d.z*d.z + d.w*d.w;
            #pragma unroll
            for (int off = 16; off > 0; off >>= 1) ss += __shfl_xor(ss, off);
            const float denom = fmaxf(sqrtf(ss), 1e-12f);
            const float r = __frcp_rn(denom);
            d.x = __fdiv_rn(d.x, denom);
            d.y = __fdiv_rn(d.y, denom);
            d.z = __fdiv_rn(d.z, denom);
            d.w = __fdiv_rn(d.w, denom);
            (void)r;
        }
        *((float4*)(out + DESC_OFF + (size_t)g * CC) + lane32) = d;
    }
}

extern "C" void kernel_launch(void* const* d_in, const int* in_sizes, int n_in,
                              void* d_out, int out_size, void* d_ws, size_t ws_size,
                              hipStream_t stream) {
    (void)in_sizes; (void)n_in; (void)out_size; (void)ws_size;
    const float* f0 = (const float*)d_in[0];
    const float* f1 = (const float*)d_in[1];
    const float* f2 = (const float*)d_in[2];
    const float* s0 = (const float*)d_in[3];
    const float* s1 = (const float*)d_in[4];
    const float* s2 = (const float*)d_in[5];
    float* out = (float*)d_out;
    float* ws  = (float*)d_ws;

    zero_sums<<<1, 64, 0, stream>>>(ws);
    prep_kernel<<<NP/256, 256, 0, stream>>>(f0, f1, f2, s0, s1, s2, out, ws);
    scale_kernel<<<NP/256, 256, 0, stream>>>(out, ws);
    desc_kernel<<<DESC_BLOCKS, 256, 0, stream>>>(ws, out);
}

// Round 3
// 228.726 us; speedup vs baseline: 1.1334x; 1.0611x over previous
//
#include <hip/hip_runtime.h>
#include <math.h>

#define CC 128
#define HH 32
#define WW 32
#define HW (HH*WW)
#define PP (CC*HW)          // 131072 per level (2^17)
#define NL 3
#define NP (NL*PP)          // 393216 total keypoints
#define PREP_BLOCKS (NP/256)   // 1536; 512 per level

// d_out layout (floats), concat in return order
#define KP_OFF   0                    // [NP,2]
#define DESC_OFF (NP*2)               // [NP,128]
#define SC_OFF   (DESC_OFF + (size_t)NP*CC) // [NP]
#define MK_OFF   (SC_OFF + NP)        // [NP]

// ws layout (floats)
#define WS_PK   ((size_t)0)           // packed {ki,kj,sm,mf} per row, 4*NP
#define WS_FT   ((size_t)4*NP)        // transposed features, [level][H*W][C], NP
#define WS_PART ((size_t)5*NP)        // per-block partial sumsq, PREP_BLOCKS
#define WS_SUM  (WS_PART + PREP_BLOCKS) // 3 per-level sums

__global__ __launch_bounds__(256) void prep_kernel(
    const float* __restrict__ f0, const float* __restrict__ f1, const float* __restrict__ f2,
    const float* __restrict__ s0, const float* __restrict__ s1, const float* __restrict__ s2,
    float* __restrict__ out, float* __restrict__ ws)
{
    const int g = blockIdx.x * 256 + threadIdx.x;     // [0, NP)
    const int level = g >> 17;                         // uniform per block
    const int p = g & (PP - 1);
    const float* __restrict__ f  = (level == 0) ? f0 : (level == 1) ? f1 : f2;
    const float* __restrict__ sc = (level == 0) ? s0 : (level == 1) ? s1 : s2;

    const int c   = p >> 10;          // p / 1024
    const int rem = p & 1023;         // i*32 + j
    const int i   = rem >> 5;
    const int j   = rem & 31;

    const float fc = f[p];
    const float* __restrict__ fb = f + (c << 10);

    // zero-padded 3x3 stencil
    #define LD(ii, jj) (((ii) >= 0 && (ii) < HH && (jj) >= 0 && (jj) < WW) ? fb[(ii)*WW + (jj)] : 0.0f)
    const float fN  = LD(i-1, j  );
    const float fS  = LD(i+1, j  );
    const float fWv = LD(i  , j-1);
    const float fE  = LD(i  , j+1);
    const float fNW = LD(i-1, j-1);
    const float fNE = LD(i-1, j+1);
    const float fSW = LD(i+1, j-1);
    const float fSE = LD(i+1, j+1);
    #undef LD

    // Replicate numpy fp32 IEEE evaluation exactly (no FMA contraction).
    const float di  = __fmul_rn(0.5f, __fsub_rn(fS, fN));
    const float dj  = __fmul_rn(0.5f, __fsub_rn(fE, fWv));
    const float dii = __fadd_rn(__fsub_rn(fS, __fmul_rn(2.0f, fc)), fN);
    const float djj = __fadd_rn(__fsub_rn(fE, __fmul_rn(2.0f, fc)), fWv);
    const float dij = __fmul_rn(0.25f, __fadd_rn(__fsub_rn(__fsub_rn(fNW, fNE), fSW), fSE));

    const float det = __fsub_rn(__fmul_rn(dii, djj), __fmul_rn(dij, dij));
    const bool det_ok = fabsf(det) > 1e-10f;
    const float det_s = det_ok ? det : 1.0f;
    const float t1 = __fsub_rn(__fmul_rn(djj, di), __fmul_rn(dij, dj));
    const float disp_i = __fdiv_rn(-t1, det_s);
    const float t2 = __fadd_rn(-__fmul_rn(dij, di), __fmul_rn(dii, dj));
    const float disp_j = __fdiv_rn(-t2, det_s);
    const bool disp_ok = det_ok && (fabsf(disp_i) < 0.5f) && (fabsf(disp_j) < 0.5f);

    const float sraw = sc[p];
    const float sth = (sraw < 0.5f) ? 0.0f : sraw;
    const bool det_mask = (sth != 0.0f);

    const float ki = __fadd_rn(disp_ok ? disp_i : 0.0f, (float)i);
    const float kj = __fadd_rn(disp_ok ? disp_j : 0.0f, (float)j);
    const float i0 = floorf(ki), i1 = ceilf(ki);
    const float j0 = floorf(kj), j1 = ceilf(kj);
    const bool in_b = (i0 >= 0.0f) && (i1 <= (float)(HH-1)) && (j0 >= 0.0f) && (j1 <= (float)(WW-1));
    const bool mask = det_mask && disp_ok && in_b;
    const float mf = mask ? 1.0f : 0.0f;

    // keypoints: kp = k*16 + 7.5, masked — packed 8B store
    float2 kpv;
    kpv.x = mask ? __fadd_rn(__fmul_rn(ki, 16.0f), 7.5f) : 0.0f;
    kpv.y = mask ? __fadd_rn(__fmul_rn(kj, 16.0f), 7.5f) : 0.0f;
    *(float2*)(out + KP_OFF + 2*(size_t)g) = kpv;
    out[MK_OFF + g] = mf;

    const float sm = mask ? sth : 0.0f;

    // packed per-row params: one coalesced 16B store
    float4 pk; pk.x = ki; pk.y = kj; pk.z = sm; pk.w = mf;
    *(float4*)(ws + WS_PK + 4*(size_t)g) = pk;

    ws[WS_FT + (size_t)level*PP + (size_t)rem*CC + c] = fc;   // [H,W,C] transpose

    // per-block partial sum of squares (no atomics)
    float v = __fmul_rn(sm, sm);
    #pragma unroll
    for (int off = 32; off > 0; off >>= 1) v += __shfl_xor(v, off);
    __shared__ float red[4];
    const int wid = threadIdx.x >> 6;
    const int lane = threadIdx.x & 63;
    if (lane == 0) red[wid] = v;
    __syncthreads();
    if (threadIdx.x == 0) {
        ws[WS_PART + blockIdx.x] = red[0] + red[1] + red[2] + red[3];
    }
}

// 3 blocks, one per level: reduce 512 partials -> ws[WS_SUM+level]
__global__ __launch_bounds__(256) void sumred_kernel(float* __restrict__ ws)
{
    const int level = blockIdx.x;
    const float* __restrict__ part = ws + WS_PART + (size_t)level * 512;
    float v = part[threadIdx.x] + part[threadIdx.x + 256];
    #pragma unroll
    for (int off = 32; off > 0; off >>= 1) v += __shfl_xor(v, off);
    __shared__ float red[4];
    const int wid = threadIdx.x >> 6;
    const int lane = threadIdx.x & 63;
    if (lane == 0) red[wid] = v;
    __syncthreads();
    if (threadIdx.x == 0) {
        ws[WS_SUM + level] = red[0] + red[1] + red[2] + red[3];
    }
}

// 32 lanes per row, float4 per lane; 8 rows per block-iteration; grid-stride.
// Fused score normalization (scale) — no separate scale kernel.
#define DESC_BLOCKS 3072
__global__ __launch_bounds__(256) void desc_kernel(const float* __restrict__ ws, float* __restrict__ out)
{
    const int sub    = threadIdx.x >> 5;   // row slot within block [0,8)
    const int lane32 = threadIdx.x & 31;

    const float sden0 = fmaxf(__fsqrt_rn(ws[WS_SUM + 0]), 1e-12f);
    const float sden1 = fmaxf(__fsqrt_rn(ws[WS_SUM + 1]), 1e-12f);
    const float sden2 = fmaxf(__fsqrt_rn(ws[WS_SUM + 2]), 1e-12f);

    for (int base = blockIdx.x * 8; base < NP; base += DESC_BLOCKS * 8) {
        const int g = base + sub;
        const int level = g >> 17;
        const float4 pk = *(const float4*)(ws + WS_PK + 4*(size_t)g);
        float4 d = make_float4(0.0f, 0.0f, 0.0f, 0.0f);

        if (pk.w != 0.0f) {
            const float ki = pk.x;
            const float kj = pk.y;
            const float i0 = floorf(ki), i1 = ceilf(ki);
            const float j0 = floorf(kj), j1 = ceilf(kj);
            const int i0c = (int)i0, i1c = (int)i1;
            const int j0c = (int)j0, j1c = (int)j1;   // mask==1 implies in-bounds
            const float di_ = ki - i0;
            const float dj_ = kj - j0;
            const float wtl = (1.0f - di_) * (1.0f - dj_);
            const float wtr = (1.0f - di_) * dj_;
            const float wbl = di_ * (1.0f - dj_);
            const float wbr = di_ * dj_;

            const float* __restrict__ ft = ws + WS_FT + (size_t)level * PP;
            const float4 tl = *((const float4*)(ft + ((size_t)(i0c*WW + j0c)) * CC) + lane32);
            const float4 tr = *((const float4*)(ft + ((size_t)(i0c*WW + j1c)) * CC) + lane32);
            const float4 bl = *((const float4*)(ft + ((size_t)(i1c*WW + j0c)) * CC) + lane32);
            const float4 br = *((const float4*)(ft + ((size_t)(i1c*WW + j1c)) * CC) + lane32);

            d.x = wtl*tl.x + wtr*tr.x + wbl*bl.x + wbr*br.x;
            d.y = wtl*tl.y + wtr*tr.y + wbl*bl.y + wbr*br.y;
            d.z = wtl*tl.z + wtr*tr.z + wbl*bl.z + wbr*br.z;
            d.w = wtl*tl.w + wtr*tr.w + wbl*bl.w + wbr*br.w;

            float ss = d.x*d.x + d.y*d.y + d.z*d.z + d.w*d.w;
            #pragma unroll
            for (int off = 16; off > 0; off >>= 1) ss += __shfl_xor(ss, off);
            const float denom = fmaxf(sqrtf(ss), 1e-12f);
            d.x = __fdiv_rn(d.x, denom);
            d.y = __fdiv_rn(d.y, denom);
            d.z = __fdiv_rn(d.z, denom);
            d.w = __fdiv_rn(d.w, denom);
        }
        *((float4*)(out + DESC_OFF + (size_t)g * CC) + lane32) = d;

        if (lane32 == 0) {
            const float sden = (level == 0) ? sden0 : (level == 1) ? sden1 : sden2;
            out[SC_OFF + g] = __fdiv_rn(pk.z, sden);
        }
    }
}

extern "C" void kernel_launch(void* const* d_in, const int* in_sizes, int n_in,
                              void* d_out, int out_size, void* d_ws, size_t ws_size,
                              hipStream_t stream) {
    (void)in_sizes; (void)n_in; (void)out_size; (void)ws_size;
    const float* f0 = (const float*)d_in[0];
    const float* f1 = (const float*)d_in[1];
    const float* f2 = (const float*)d_in[2];
    const float* s0 = (const float*)d_in[3];
    const float* s1 = (const float*)d_in[4];
    const float* s2 = (const float*)d_in[5];
    float* out = (float*)d_out;
    float* ws  = (float*)d_ws;

    prep_kernel<<<PREP_BLOCKS, 256, 0, stream>>>(f0, f1, f2, s0, s1, s2, out, ws);
    sumred_kernel<<<NL, 256, 0, stream>>>(ws);
    desc_kernel<<<DESC_BLOCKS, 256, 0, stream>>>(ws, out);
}

// Round 4
// 227.750 us; speedup vs baseline: 1.1383x; 1.0043x over previous
//
#include <hip/hip_runtime.h>
#include <math.h>

#define CC 128
#define HH 32
#define WW 32
#define HW (HH*WW)
#define PP (CC*HW)          // 131072 per level (2^17)
#define NL 3
#define NP (NL*PP)          // 393216 total keypoints
#define PREP_BLOCKS (NP/256)    // 1536; 512 per level
#define TRANS_BLOCKS (NL*4*32)  // 384: per level, 4 c-tiles x 32 pix-tiles of 32x32

// d_out layout (floats), concat in return order
#define KP_OFF   0                    // [NP,2]
#define DESC_OFF (NP*2)               // [NP,128]
#define SC_OFF   (DESC_OFF + (size_t)NP*CC) // [NP]
#define MK_OFF   (SC_OFF + NP)        // [NP]

// ws layout (floats)
#define WS_PK   ((size_t)0)           // packed {ki,kj,sm,mf} per row, 4*NP
#define WS_FT   ((size_t)4*NP)        // transposed features, [level][H*W][C], NP
#define WS_PART ((size_t)5*NP)        // per-block partial sumsq, PREP_BLOCKS

// Fused: blocks [0,PREP_BLOCKS) do per-pixel localization; blocks
// [PREP_BLOCKS, PREP_BLOCKS+TRANS_BLOCKS) do the tiled [C,H,W]->[H,W,C] transpose.
__global__ __launch_bounds__(256) void prep_kernel(
    const float* __restrict__ f0, const float* __restrict__ f1, const float* __restrict__ f2,
    const float* __restrict__ s0, const float* __restrict__ s1, const float* __restrict__ s2,
    float* __restrict__ out, float* __restrict__ ws)
{
    __shared__ float lds_buf[32*33];   // transpose tile; first 4 floats double as prep's reduce buf

    if (blockIdx.x >= PREP_BLOCKS) {
        // ---- tiled transpose: 32 channels x 32 pixels per block ----
        const int b = blockIdx.x - PREP_BLOCKS;     // 0..383
        const int level = b >> 7;                   // /128
        const int t = b & 127;
        const int c0 = (t >> 5) << 5;               // channel tile base
        const int p0 = (t & 31) << 5;               // pixel tile base
        const float* __restrict__ f = (level == 0) ? f0 : (level == 1) ? f1 : f2;
        const int pj  = threadIdx.x & 31;
        const int ci4 = threadIdx.x >> 5;           // 0..7
        #pragma unroll
        for (int k = 0; k < 4; ++k) {
            const int ci = ci4 + (k << 3);
            lds_buf[ci*33 + pj] = f[(size_t)(c0 + ci)*HW + p0 + pj];   // 128B coalesced
        }
        __syncthreads();
        float* __restrict__ ftl = ws + WS_FT + (size_t)level*PP;
        #pragma unroll
        for (int k = 0; k < 4; ++k) {
            const int ri = ci4 + (k << 3);
            ftl[(size_t)(p0 + ri)*CC + c0 + pj] = lds_buf[pj*33 + ri]; // 128B coalesced
        }
        return;
    }

    const int g = blockIdx.x * 256 + threadIdx.x;     // [0, NP)
    const int level = g >> 17;                         // uniform per block
    const int p = g & (PP - 1);
    const float* __restrict__ f  = (level == 0) ? f0 : (level == 1) ? f1 : f2;
    const float* __restrict__ sc = (level == 0) ? s0 : (level == 1) ? s1 : s2;

    const int c   = p >> 10;          // p / 1024
    const int rem = p & 1023;         // i*32 + j
    const int i   = rem >> 5;
    const int j   = rem & 31;

    const float fc = f[p];
    const float* __restrict__ fb = f + (c << 10);

    // zero-padded 3x3 stencil
    #define LD(ii, jj) (((ii) >= 0 && (ii) < HH && (jj) >= 0 && (jj) < WW) ? fb[(ii)*WW + (jj)] : 0.0f)
    const float fN  = LD(i-1, j  );
    const float fS  = LD(i+1, j  );
    const float fWv = LD(i  , j-1);
    const float fE  = LD(i  , j+1);
    const float fNW = LD(i-1, j-1);
    const float fNE = LD(i-1, j+1);
    const float fSW = LD(i+1, j-1);
    const float fSE = LD(i+1, j+1);
    #undef LD

    // Replicate numpy fp32 IEEE evaluation exactly (no FMA contraction).
    const float di  = __fmul_rn(0.5f, __fsub_rn(fS, fN));
    const float dj  = __fmul_rn(0.5f, __fsub_rn(fE, fWv));
    const float dii = __fadd_rn(__fsub_rn(fS, __fmul_rn(2.0f, fc)), fN);
    const float djj = __fadd_rn(__fsub_rn(fE, __fmul_rn(2.0f, fc)), fWv);
    const float dij = __fmul_rn(0.25f, __fadd_rn(__fsub_rn(__fsub_rn(fNW, fNE), fSW), fSE));

    const float det = __fsub_rn(__fmul_rn(dii, djj), __fmul_rn(dij, dij));
    const bool det_ok = fabsf(det) > 1e-10f;
    const float det_s = det_ok ? det : 1.0f;
    const float t1 = __fsub_rn(__fmul_rn(djj, di), __fmul_rn(dij, dj));
    const float disp_i = __fdiv_rn(-t1, det_s);
    const float t2 = __fadd_rn(-__fmul_rn(dij, di), __fmul_rn(dii, dj));
    const float disp_j = __fdiv_rn(-t2, det_s);
    const bool disp_ok = det_ok && (fabsf(disp_i) < 0.5f) && (fabsf(disp_j) < 0.5f);

    const float sraw = sc[p];
    const float sth = (sraw < 0.5f) ? 0.0f : sraw;
    const bool det_mask = (sth != 0.0f);

    const float ki = __fadd_rn(disp_ok ? disp_i : 0.0f, (float)i);
    const float kj = __fadd_rn(disp_ok ? disp_j : 0.0f, (float)j);
    const float i0 = floorf(ki), i1 = ceilf(ki);
    const float j0 = floorf(kj), j1 = ceilf(kj);
    const bool in_b = (i0 >= 0.0f) && (i1 <= (float)(HH-1)) && (j0 >= 0.0f) && (j1 <= (float)(WW-1));
    const bool mask = det_mask && disp_ok && in_b;
    const float mf = mask ? 1.0f : 0.0f;

    // keypoints: kp = k*16 + 7.5, masked — packed 8B store
    float2 kpv;
    kpv.x = mask ? __fadd_rn(__fmul_rn(ki, 16.0f), 7.5f) : 0.0f;
    kpv.y = mask ? __fadd_rn(__fmul_rn(kj, 16.0f), 7.5f) : 0.0f;
    *(float2*)(out + KP_OFF + 2*(size_t)g) = kpv;
    out[MK_OFF + g] = mf;

    const float sm = mask ? sth : 0.0f;

    // packed per-row params: one coalesced 16B store
    float4 pk; pk.x = ki; pk.y = kj; pk.z = sm; pk.w = mf;
    *(float4*)(ws + WS_PK + 4*(size_t)g) = pk;

    // per-block partial sum of squares (no atomics)
    float v = __fmul_rn(sm, sm);
    #pragma unroll
    for (int off = 32; off > 0; off >>= 1) v += __shfl_xor(v, off);
    const int wid = threadIdx.x >> 6;
    const int lane = threadIdx.x & 63;
    if (lane == 0) lds_buf[wid] = v;
    __syncthreads();
    if (threadIdx.x == 0) {
        ws[WS_PART + blockIdx.x] = lds_buf[0] + lds_buf[1] + lds_buf[2] + lds_buf[3];
    }
}

// 32 lanes per row, float4 per lane; 8 rows per block-iteration; grid-stride.
// Per-level score denominators computed redundantly per block (partials are L2-hot).
#define DESC_BLOCKS 3072
__global__ __launch_bounds__(256) void desc_kernel(const float* __restrict__ ws, float* __restrict__ out)
{
    __shared__ float red[4];
    __shared__ float sden_sh[NL];

    // reduce 512 partials per level -> denominator
    const float* __restrict__ part = ws + WS_PART;
    for (int l = 0; l < NL; ++l) {
        float v = part[l*512 + threadIdx.x] + part[l*512 + threadIdx.x + 256];
        #pragma unroll
        for (int off = 32; off > 0; off >>= 1) v += __shfl_xor(v, off);
        const int wid = threadIdx.x >> 6;
        const int lane = threadIdx.x & 63;
        if (lane == 0) red[wid] = v;
        __syncthreads();
        if (threadIdx.x == 0) {
            sden_sh[l] = fmaxf(__fsqrt_rn(red[0] + red[1] + red[2] + red[3]), 1e-12f);
        }
        __syncthreads();
    }

    const int sub    = threadIdx.x >> 5;   // row slot within block [0,8)
    const int lane32 = threadIdx.x & 31;

    for (int base = blockIdx.x * 8; base < NP; base += DESC_BLOCKS * 8) {
        const int g = base + sub;
        const int level = g >> 17;
        const float4 pk = *(const float4*)(ws + WS_PK + 4*(size_t)g);
        float4 d = make_float4(0.0f, 0.0f, 0.0f, 0.0f);

        if (pk.w != 0.0f) {
            const float ki = pk.x;
            const float kj = pk.y;
            const float i0 = floorf(ki), i1 = ceilf(ki);
            const float j0 = floorf(kj), j1 = ceilf(kj);
            const int i0c = (int)i0, i1c = (int)i1;
            const int j0c = (int)j0, j1c = (int)j1;   // mask==1 implies in-bounds
            const float di_ = ki - i0;
            const float dj_ = kj - j0;
            const float wtl = (1.0f - di_) * (1.0f - dj_);
            const float wtr = (1.0f - di_) * dj_;
            const float wbl = di_ * (1.0f - dj_);
            const float wbr = di_ * dj_;

            const float* __restrict__ ft = ws + WS_FT + (size_t)level * PP;
            const float4 tl = *((const float4*)(ft + ((size_t)(i0c*WW + j0c)) * CC) + lane32);
            const float4 tr = *((const float4*)(ft + ((size_t)(i0c*WW + j1c)) * CC) + lane32);
            const float4 bl = *((const float4*)(ft + ((size_t)(i1c*WW + j0c)) * CC) + lane32);
            const float4 br = *((const float4*)(ft + ((size_t)(i1c*WW + j1c)) * CC) + lane32);

            d.x = wtl*tl.x + wtr*tr.x + wbl*bl.x + wbr*br.x;
            d.y = wtl*tl.y + wtr*tr.y + wbl*bl.y + wbr*br.y;
            d.z = wtl*tl.z + wtr*tr.z + wbl*bl.z + wbr*br.z;
            d.w = wtl*tl.w + wtr*tr.w + wbl*bl.w + wbr*br.w;

            float ss = d.x*d.x + d.y*d.y + d.z*d.z + d.w*d.w;
            #pragma unroll
            for (int off = 16; off > 0; off >>= 1) ss += __shfl_xor(ss, off);
            const float denom = fmaxf(sqrtf(ss), 1e-12f);
            d.x = __fdiv_rn(d.x, denom);
            d.y = __fdiv_rn(d.y, denom);
            d.z = __fdiv_rn(d.z, denom);
            d.w = __fdiv_rn(d.w, denom);
        }
        *((float4*)(out + DESC_OFF + (size_t)g * CC) + lane32) = d;

        if (lane32 == 0) {
            out[SC_OFF + g] = __fdiv_rn(pk.z, sden_sh[level]);
        }
    }
}

extern "C" void kernel_launch(void* const* d_in, const int* in_sizes, int n_in,
                              void* d_out, int out_size, void* d_ws, size_t ws_size,
                              hipStream_t stream) {
    (void)in_sizes; (void)n_in; (void)out_size; (void)ws_size;
    const float* f0 = (const float*)d_in[0];
    const float* f1 = (const float*)d_in[1];
    const float* f2 = (const float*)d_in[2];
    const float* s0 = (const float*)d_in[3];
    const float* s1 = (const float*)d_in[4];
    const float* s2 = (const float*)d_in[5];
    float* out = (float*)d_out;
    float* ws  = (float*)d_ws;

    prep_kernel<<<PREP_BLOCKS + TRANS_BLOCKS, 256, 0, stream>>>(f0, f1, f2, s0, s1, s2, out, ws);
    desc_kernel<<<DESC_BLOCKS, 256, 0, stream>>>(ws, out);
}

// Round 5
// 226.809 us; speedup vs baseline: 1.1430x; 1.0041x over previous
//
#include <hip/hip_runtime.h>
#include <math.h>

#define CC 128
#define HH 32
#define WW 32
#define HW (HH*WW)
#define PP (CC*HW)          // 131072 per level (2^17)
#define NL 3
#define NP (NL*PP)          // 393216 total keypoints
#define PREP_BLOCKS (NP/256)    // 1536; 512 per level
#define TRANS_BLOCKS (NL*4*32)  // 384: per level, 4 c-tiles x 32 pix-tiles of 32x32

// d_out layout (floats), concat in return order
#define KP_OFF   0                    // [NP,2]
#define DESC_OFF (NP*2)               // [NP,128]
#define SC_OFF   (DESC_OFF + (size_t)NP*CC) // [NP]
#define MK_OFF   (SC_OFF + NP)        // [NP]

// ws layout (floats)
#define WS_PK   ((size_t)0)           // float2 {ki,kj} per row: 2*NP
#define WS_SM   ((size_t)2*NP)        // masked score per row: NP  (sm!=0 <=> mask)
#define WS_FT   ((size_t)3*NP)        // transposed features, [level][H*W][C]: NP
#define WS_PART ((size_t)4*NP)        // per-block partial sumsq: PREP_BLOCKS
#define WS_CNT  (WS_PART + PREP_BLOCKS)   // per-block masked count (int): PREP_BLOCKS
#define WS_LIST (WS_CNT + PREP_BLOCKS)    // per-block segment lists (int), 256 each: NP

// Fused: blocks [0,PREP_BLOCKS) localization+compaction; rest: tiled transpose.
__global__ __launch_bounds__(256) void prep_kernel(
    const float* __restrict__ f0, const float* __restrict__ f1, const float* __restrict__ f2,
    const float* __restrict__ s0, const float* __restrict__ s1, const float* __restrict__ s2,
    float* __restrict__ out, float* __restrict__ ws)
{
    __shared__ float lds_buf[32*33];   // transpose tile
    __shared__ float redbuf[4];
    __shared__ int   wcnt[4];

    if (blockIdx.x >= PREP_BLOCKS) {
        // ---- tiled transpose: 32 channels x 32 pixels per block ----
        const int b = blockIdx.x - PREP_BLOCKS;     // 0..383
        const int level = b >> 7;
        const int t = b & 127;
        const int c0 = (t >> 5) << 5;
        const int p0 = (t & 31) << 5;
        const float* __restrict__ f = (level == 0) ? f0 : (level == 1) ? f1 : f2;
        const int pj  = threadIdx.x & 31;
        const int ci4 = threadIdx.x >> 5;
        #pragma unroll
        for (int k = 0; k < 4; ++k) {
            const int ci = ci4 + (k << 3);
            lds_buf[ci*33 + pj] = f[(size_t)(c0 + ci)*HW + p0 + pj];
        }
        __syncthreads();
        float* __restrict__ ftl = ws + WS_FT + (size_t)level*PP;
        #pragma unroll
        for (int k = 0; k < 4; ++k) {
            const int ri = ci4 + (k << 3);
            ftl[(size_t)(p0 + ri)*CC + c0 + pj] = lds_buf[pj*33 + ri];
        }
        return;
    }

    const int g = blockIdx.x * 256 + threadIdx.x;     // [0, NP)
    const int level = g >> 17;                         // uniform per block
    const int p = g & (PP - 1);
    const float* __restrict__ f  = (level == 0) ? f0 : (level == 1) ? f1 : f2;
    const float* __restrict__ sc = (level == 0) ? s0 : (level == 1) ? s1 : s2;

    const int c   = p >> 10;
    const int rem = p & 1023;
    const int i   = rem >> 5;
    const int j   = rem & 31;

    const float fc = f[p];
    const float* __restrict__ fb = f + (c << 10);

    // zero-padded 3x3 stencil
    #define LD(ii, jj) (((ii) >= 0 && (ii) < HH && (jj) >= 0 && (jj) < WW) ? fb[(ii)*WW + (jj)] : 0.0f)
    const float fN  = LD(i-1, j  );
    const float fS  = LD(i+1, j  );
    const float fWv = LD(i  , j-1);
    const float fE  = LD(i  , j+1);
    const float fNW = LD(i-1, j-1);
    const float fNE = LD(i-1, j+1);
    const float fSW = LD(i+1, j-1);
    const float fSE = LD(i+1, j+1);
    #undef LD

    // Replicate numpy fp32 IEEE evaluation exactly (no FMA contraction).
    const float di  = __fmul_rn(0.5f, __fsub_rn(fS, fN));
    const float dj  = __fmul_rn(0.5f, __fsub_rn(fE, fWv));
    const float dii = __fadd_rn(__fsub_rn(fS, __fmul_rn(2.0f, fc)), fN);
    const float djj = __fadd_rn(__fsub_rn(fE, __fmul_rn(2.0f, fc)), fWv);
    const float dij = __fmul_rn(0.25f, __fadd_rn(__fsub_rn(__fsub_rn(fNW, fNE), fSW), fSE));

    const float det = __fsub_rn(__fmul_rn(dii, djj), __fmul_rn(dij, dij));
    const bool det_ok = fabsf(det) > 1e-10f;
    const float det_s = det_ok ? det : 1.0f;
    const float t1 = __fsub_rn(__fmul_rn(djj, di), __fmul_rn(dij, dj));
    const float disp_i = __fdiv_rn(-t1, det_s);
    const float t2 = __fadd_rn(-__fmul_rn(dij, di), __fmul_rn(dii, dj));
    const float disp_j = __fdiv_rn(-t2, det_s);
    const bool disp_ok = det_ok && (fabsf(disp_i) < 0.5f) && (fabsf(disp_j) < 0.5f);

    const float sraw = sc[p];
    const float sth = (sraw < 0.5f) ? 0.0f : sraw;
    const bool det_mask = (sth != 0.0f);

    const float ki = __fadd_rn(disp_ok ? disp_i : 0.0f, (float)i);
    const float kj = __fadd_rn(disp_ok ? disp_j : 0.0f, (float)j);
    const float i0 = floorf(ki), i1 = ceilf(ki);
    const float j0 = floorf(kj), j1 = ceilf(kj);
    const bool in_b = (i0 >= 0.0f) && (i1 <= (float)(HH-1)) && (j0 >= 0.0f) && (j1 <= (float)(WW-1));
    const bool mask = det_mask && disp_ok && in_b;
    const float mf = mask ? 1.0f : 0.0f;

    float2 kpv;
    kpv.x = mask ? __fadd_rn(__fmul_rn(ki, 16.0f), 7.5f) : 0.0f;
    kpv.y = mask ? __fadd_rn(__fmul_rn(kj, 16.0f), 7.5f) : 0.0f;
    *(float2*)(out + KP_OFF + 2*(size_t)g) = kpv;
    out[MK_OFF + g] = mf;

    const float sm = mask ? sth : 0.0f;
    ws[WS_SM + g] = sm;

    float2 pk; pk.x = ki; pk.y = kj;
    *(float2*)(ws + WS_PK + 2*(size_t)g) = pk;

    // per-block partial sumsq + masked-row compaction (no atomics)
    const int lane = threadIdx.x & 63;
    const int wid  = threadIdx.x >> 6;
    float v = __fmul_rn(sm, sm);
    #pragma unroll
    for (int off = 32; off > 0; off >>= 1) v += __shfl_xor(v, off);
    const unsigned long long bal = __ballot(mask);
    if (lane == 0) { redbuf[wid] = v; wcnt[wid] = (int)__popcll(bal); }
    __syncthreads();
    if (mask) {
        int base = 0;
        #pragma unroll
        for (int w = 0; w < 4; ++w) base += (w < wid) ? wcnt[w] : 0;
        const int off = (int)__popcll(bal & ((1ULL << lane) - 1ULL));
        ((int*)(ws + WS_LIST))[blockIdx.x*256 + base + off] = g;
    }
    if (threadIdx.x == 0) {
        ws[WS_PART + blockIdx.x] = redbuf[0] + redbuf[1] + redbuf[2] + redbuf[3];
        ((int*)(ws + WS_CNT))[blockIdx.x] = wcnt[0] + wcnt[1] + wcnt[2] + wcnt[3];
    }
}

// Fused second stage, block-partitioned:
//   blocks [0, ZB): scores (all rows) + zero-fill of UNMASKED descriptor rows (pure streaming)
//   blocks [ZB, ZB+PREP_BLOCKS): sparse bilinear descriptors for masked rows (compact lists)
#define ZB 6144
__global__ __launch_bounds__(256) void desc2_kernel(const float* __restrict__ ws, float* __restrict__ out)
{
    __shared__ float red[4];
    __shared__ float sden_sh[NL];

    if (blockIdx.x < ZB) {
        // ---- denominators ----
        const float* __restrict__ part = ws + WS_PART;
        for (int l = 0; l < NL; ++l) {
            float v = part[l*512 + threadIdx.x] + part[l*512 + threadIdx.x + 256];
            #pragma unroll
            for (int off = 32; off > 0; off >>= 1) v += __shfl_xor(v, off);
            const int wid = threadIdx.x >> 6;
            const int lane = threadIdx.x & 63;
            if (lane == 0) red[wid] = v;
            __syncthreads();
            if (threadIdx.x == 0)
                sden_sh[l] = fmaxf(__fsqrt_rn(red[0] + red[1] + red[2] + red[3]), 1e-12f);
            __syncthreads();
        }
        // ---- scores: coalesced 4B/lane ----
        {
            const int idx = blockIdx.x * 256 + threadIdx.x;   // ZB*256 = 4*NP/... covers NP in first quarter
            if (idx < NP) {
                const float s = ws[WS_SM + idx];
                out[SC_OFF + idx] = __fdiv_rn(s, sden_sh[idx >> 17]);
            }
        }
        // ---- zero-fill unmasked descriptor rows: branch-free chain, store-bound ----
        const int sub    = threadIdx.x >> 5;
        const int lane32 = threadIdx.x & 31;
        const float4 z4 = make_float4(0.0f, 0.0f, 0.0f, 0.0f);
        for (int base = blockIdx.x * 8; base < NP; base += ZB * 8) {   // 8 iterations
            const int g = base + sub;
            if (ws[WS_SM + g] == 0.0f) {
                *((float4*)(out + DESC_OFF + (size_t)g * CC) + lane32) = z4;
            }
        }
        return;
    }

    // ---- sparse descriptor compute: only masked rows ----
    const int seg = blockIdx.x - ZB;                  // [0, PREP_BLOCKS)
    const int cnt = ((const int*)(ws + WS_CNT))[seg];
    const int* __restrict__ list = (const int*)(ws + WS_LIST) + seg*256;
    const int sub    = threadIdx.x >> 5;
    const int lane32 = threadIdx.x & 31;

    for (int idx = sub; idx < cnt; idx += 8) {
        const int g = list[idx];
        const int level = g >> 17;
        const float2 pk = *(const float2*)(ws + WS_PK + 2*(size_t)g);
        const float ki = pk.x;
        const float kj = pk.y;
        const float i0 = floorf(ki), i1 = ceilf(ki);
        const float j0 = floorf(kj), j1 = ceilf(kj);
        const int i0c = (int)i0, i1c = (int)i1;
        const int j0c = (int)j0, j1c = (int)j1;       // masked => in-bounds
        const float di_ = ki - i0;
        const float dj_ = kj - j0;
        const float wtl = (1.0f - di_) * (1.0f - dj_);
        const float wtr = (1.0f - di_) * dj_;
        const float wbl = di_ * (1.0f - dj_);
        const float wbr = di_ * dj_;

        const float* __restrict__ ft = ws + WS_FT + (size_t)level * PP;
        const float4 tl = *((const float4*)(ft + ((size_t)(i0c*WW + j0c)) * CC) + lane32);
        const float4 tr = *((const float4*)(ft + ((size_t)(i0c*WW + j1c)) * CC) + lane32);
        const float4 bl = *((const float4*)(ft + ((size_t)(i1c*WW + j0c)) * CC) + lane32);
        const float4 br = *((const float4*)(ft + ((size_t)(i1c*WW + j1c)) * CC) + lane32);

        float4 d;
        d.x = wtl*tl.x + wtr*tr.x + wbl*bl.x + wbr*br.x;
        d.y = wtl*tl.y + wtr*tr.y + wbl*bl.y + wbr*br.y;
        d.z = wtl*tl.z + wtr*tr.z + wbl*bl.z + wbr*br.z;
        d.w = wtl*tl.w + wtr*tr.w + wbl*bl.w + wbr*br.w;

        float ss = d.x*d.x + d.y*d.y + d.z*d.z + d.w*d.w;
        #pragma unroll
        for (int off = 16; off > 0; off >>= 1) ss += __shfl_xor(ss, off);
        const float denom = fmaxf(sqrtf(ss), 1e-12f);
        d.x = __fdiv_rn(d.x, denom);
        d.y = __fdiv_rn(d.y, denom);
        d.z = __fdiv_rn(d.z, denom);
        d.w = __fdiv_rn(d.w, denom);

        *((float4*)(out + DESC_OFF + (size_t)g * CC) + lane32) = d;
    }
}

extern "C" void kernel_launch(void* const* d_in, const int* in_sizes, int n_in,
                              void* d_out, int out_size, void* d_ws, size_t ws_size,
                              hipStream_t stream) {
    (void)in_sizes; (void)n_in; (void)out_size; (void)ws_size;
    const float* f0 = (const float*)d_in[0];
    const float* f1 = (const float*)d_in[1];
    const float* f2 = (const float*)d_in[2];
    const float* s0 = (const float*)d_in[3];
    const float* s1 = (const float*)d_in[4];
    const float* s2 = (const float*)d_in[5];
    float* out = (float*)d_out;
    float* ws  = (float*)d_ws;

    prep_kernel<<<PREP_BLOCKS + TRANS_BLOCKS, 256, 0, stream>>>(f0, f1, f2, s0, s1, s2, out, ws);
    desc2_kernel<<<ZB + PREP_BLOCKS, 256, 0, stream>>>(ws, out);
}